// Round 1
// baseline (1978.786 us; speedup 1.0000x reference)
//
#include <hip/hip_runtime.h>

#define NN 50000
#define NE 800000
#define D  128
#define LN_EPS 1e-5f

__device__ __forceinline__ float gelu_f(float x) {
    return 0.5f * x * (1.0f + erff(x * 0.70710678118654752440f));
}

// OUT = LN(gelu(X @ W))            [MODE 0]
// OUT += alpha * LN(gelu(X @ W))   [MODE 1]
// If gate != nullptr and *gate == 0, kernel is a no-op (uniform branch).
template<int MODE>
__global__ __launch_bounds__(256, 2)
void proj_kernel(const float* __restrict__ X, const float* __restrict__ W,
                 const float* __restrict__ g, const float* __restrict__ bb,
                 float* __restrict__ OUT, int M,
                 const float* __restrict__ gate)
{
    if (gate && gate[0] == 0.0f) return;
    extern __shared__ float sm[];
    float* Ws = sm;             // 128x128 = 64KB
    float* xs = sm + D * D;     // 32x128  = 16KB
    const int t = threadIdx.x;

    { // stage W -> LDS (coalesced float4)
        const float4* Wg = (const float4*)W;
        float4* Wl = (float4*)Ws;
        #pragma unroll
        for (int i = 0; i < 16; ++i) Wl[t + 256 * i] = Wg[t + 256 * i];
    }
    const int row0 = blockIdx.x * 32;
    { // stage 32-row X tile -> LDS, zero-pad OOB rows
        const float4* Xg = (const float4*)X;
        float4* xl = (float4*)xs;
        #pragma unroll
        for (int i = 0; i < 4; ++i) {
            int idx = t + 256 * i;            // [0,1024) float4s
            int r = row0 + (idx >> 5);
            float4 v = make_float4(0.f, 0.f, 0.f, 0.f);
            if (r < M) v = Xg[(size_t)r * 32 + (idx & 31)];
            xl[idx] = v;
        }
    }
    __syncthreads();

    const int c4 = t & 31;    // column quad (4 cols)
    const int rg = t >> 5;    // row group (4 rows)
    float acc[4][4];
    #pragma unroll
    for (int j = 0; j < 4; ++j)
        #pragma unroll
        for (int i = 0; i < 4; ++i) acc[j][i] = 0.f;

    const float* xr = xs + rg * 4 * D;
    const float4* Wv = (const float4*)Ws;
    #pragma unroll 8
    for (int k = 0; k < D; ++k) {
        float4 w = Wv[k * 32 + c4];
        float x0 = xr[k], x1 = xr[D + k], x2 = xr[2 * D + k], x3 = xr[3 * D + k];
        acc[0][0] = fmaf(x0, w.x, acc[0][0]); acc[0][1] = fmaf(x0, w.y, acc[0][1]);
        acc[0][2] = fmaf(x0, w.z, acc[0][2]); acc[0][3] = fmaf(x0, w.w, acc[0][3]);
        acc[1][0] = fmaf(x1, w.x, acc[1][0]); acc[1][1] = fmaf(x1, w.y, acc[1][1]);
        acc[1][2] = fmaf(x1, w.z, acc[1][2]); acc[1][3] = fmaf(x1, w.w, acc[1][3]);
        acc[2][0] = fmaf(x2, w.x, acc[2][0]); acc[2][1] = fmaf(x2, w.y, acc[2][1]);
        acc[2][2] = fmaf(x2, w.z, acc[2][2]); acc[2][3] = fmaf(x2, w.w, acc[2][3]);
        acc[3][0] = fmaf(x3, w.x, acc[3][0]); acc[3][1] = fmaf(x3, w.y, acc[3][1]);
        acc[3][2] = fmaf(x3, w.z, acc[3][2]); acc[3][3] = fmaf(x3, w.w, acc[3][3]);
    }

    float4 gw = *(const float4*)(g + c4 * 4);
    float4 bw = *(const float4*)(bb + c4 * 4);
    float alpha = (MODE == 1) ? gate[0] : 0.0f;

    #pragma unroll
    for (int j = 0; j < 4; ++j) {
        float v0 = gelu_f(acc[j][0]);
        float v1 = gelu_f(acc[j][1]);
        float v2 = gelu_f(acc[j][2]);
        float v3 = gelu_f(acc[j][3]);
        float s  = v0 + v1 + v2 + v3;
        float s2 = v0 * v0 + v1 * v1 + v2 * v2 + v3 * v3;
        #pragma unroll
        for (int m = 16; m >= 1; m >>= 1) {  // reduce across the 32 lanes of this row
            s  += __shfl_xor(s,  m, 64);
            s2 += __shfl_xor(s2, m, 64);
        }
        float mean = s * (1.0f / 128.0f);
        float var  = s2 * (1.0f / 128.0f) - mean * mean;
        float rstd = rsqrtf(var + LN_EPS);
        int r = row0 + rg * 4 + j;
        if (r < M) {
            float4 o;
            o.x = (v0 - mean) * rstd * gw.x + bw.x;
            o.y = (v1 - mean) * rstd * gw.y + bw.y;
            o.z = (v2 - mean) * rstd * gw.z + bw.z;
            o.w = (v3 - mean) * rstd * gw.w + bw.w;
            float4* po = (float4*)(OUT + (size_t)r * D + c4 * 4);
            if (MODE == 1) {
                float4 p = *po;
                o.x = p.x + alpha * o.x; o.y = p.y + alpha * o.y;
                o.z = p.z + alpha * o.z; o.w = p.w + alpha * o.w;
            }
            *po = o;
        }
    }
}

// per edge e: he = exp(LN(EF[e] @ W)); h[dst[e]] += hv[src[e]] * he
__global__ __launch_bounds__(256, 2)
void edge_kernel(const float* __restrict__ EF, const float* __restrict__ W,
                 const float* __restrict__ g, const float* __restrict__ bb,
                 const float* __restrict__ hv,
                 const int* __restrict__ src, const int* __restrict__ dst,
                 float* __restrict__ h, const float* __restrict__ gate)
{
    if (gate && gate[0] == 0.0f) return;
    extern __shared__ float sm[];
    float* Ws = sm;           // 64KB
    float* es = sm + D * D;   // 16KB (32 edges x 128)
    const int t = threadIdx.x;
    {
        const float4* Wg = (const float4*)W;
        float4* Wl = (float4*)Ws;
        #pragma unroll
        for (int i = 0; i < 16; ++i) Wl[t + 256 * i] = Wg[t + 256 * i];
    }
    const int c4 = t & 31;
    const int rg = t >> 5;
    const float4 gw = *(const float4*)(g + c4 * 4);
    const float4 bw = *(const float4*)(bb + c4 * 4);
    const float4* Wv = (const float4*)Ws;

    for (int chunk = blockIdx.x; chunk < NE / 32; chunk += gridDim.x) {
        __syncthreads();   // protect es from previous iteration's readers
        const int e0 = chunk * 32;
        {
            const float4* Eg = (const float4*)EF + (size_t)e0 * 32;
            float4* el = (float4*)es;
            #pragma unroll
            for (int i = 0; i < 4; ++i) el[t + 256 * i] = Eg[t + 256 * i];
        }
        __syncthreads();

        float acc[4][4];
        #pragma unroll
        for (int j = 0; j < 4; ++j)
            #pragma unroll
            for (int i = 0; i < 4; ++i) acc[j][i] = 0.f;

        const float* er = es + rg * 4 * D;
        #pragma unroll 8
        for (int k = 0; k < D; ++k) {
            float4 w = Wv[k * 32 + c4];
            float x0 = er[k], x1 = er[D + k], x2 = er[2 * D + k], x3 = er[3 * D + k];
            acc[0][0] = fmaf(x0, w.x, acc[0][0]); acc[0][1] = fmaf(x0, w.y, acc[0][1]);
            acc[0][2] = fmaf(x0, w.z, acc[0][2]); acc[0][3] = fmaf(x0, w.w, acc[0][3]);
            acc[1][0] = fmaf(x1, w.x, acc[1][0]); acc[1][1] = fmaf(x1, w.y, acc[1][1]);
            acc[1][2] = fmaf(x1, w.z, acc[1][2]); acc[1][3] = fmaf(x1, w.w, acc[1][3]);
            acc[2][0] = fmaf(x2, w.x, acc[2][0]); acc[2][1] = fmaf(x2, w.y, acc[2][1]);
            acc[2][2] = fmaf(x2, w.z, acc[2][2]); acc[2][3] = fmaf(x2, w.w, acc[2][3]);
            acc[3][0] = fmaf(x3, w.x, acc[3][0]); acc[3][1] = fmaf(x3, w.y, acc[3][1]);
            acc[3][2] = fmaf(x3, w.z, acc[3][2]); acc[3][3] = fmaf(x3, w.w, acc[3][3]);
        }

        #pragma unroll
        for (int j = 0; j < 4; ++j) {
            float v0 = acc[j][0], v1 = acc[j][1], v2 = acc[j][2], v3 = acc[j][3];
            float s  = v0 + v1 + v2 + v3;
            float s2 = v0 * v0 + v1 * v1 + v2 * v2 + v3 * v3;
            #pragma unroll
            for (int m = 16; m >= 1; m >>= 1) {
                s  += __shfl_xor(s,  m, 64);
                s2 += __shfl_xor(s2, m, 64);
            }
            float mean = s * (1.0f / 128.0f);
            float var  = s2 * (1.0f / 128.0f) - mean * mean;
            float rstd = rsqrtf(var + LN_EPS);
            int e = e0 + rg * 4 + j;
            int sr = src[e];
            int dr = dst[e];
            float4 m4 = ((const float4*)(hv + (size_t)sr * D))[c4];
            float h0 = expf((v0 - mean) * rstd * gw.x + bw.x) * m4.x;
            float h1 = expf((v1 - mean) * rstd * gw.y + bw.y) * m4.y;
            float h2 = expf((v2 - mean) * rstd * gw.z + bw.z) * m4.z;
            float h3 = expf((v3 - mean) * rstd * gw.w + bw.w) * m4.w;
            float* hp = h + (size_t)dr * D + c4 * 4;
            atomicAdd(hp + 0, h0);
            atomicAdd(hp + 1, h1);
            atomicAdd(hp + 2, h2);
            atomicAdd(hp + 3, h3);
        }
    }
}

// x = out + belta * node_feats   (block input for i>0), gated on alpha != 0
__global__ __launch_bounds__(256)
void prep_kernel(const float* __restrict__ out, const float* __restrict__ nf,
                 const float* __restrict__ belta, const float* __restrict__ gate,
                 float* __restrict__ x)
{
    if (gate[0] == 0.0f) return;
    const float bv = belta[0];
    const int n4 = NN * D / 4;
    const float4* o4 = (const float4*)out;
    const float4* f4 = (const float4*)nf;
    float4* x4 = (float4*)x;
    for (int i = blockIdx.x * blockDim.x + threadIdx.x; i < n4; i += gridDim.x * blockDim.x) {
        float4 a = o4[i], b = f4[i];
        a.x = fmaf(bv, b.x, a.x); a.y = fmaf(bv, b.y, a.y);
        a.z = fmaf(bv, b.z, a.z); a.w = fmaf(bv, b.w, a.w);
        x4[i] = a;
    }
}

extern "C" void kernel_launch(void* const* d_in, const int* in_sizes, int n_in,
                              void* d_out, int out_size, void* d_ws, size_t ws_size,
                              hipStream_t stream)
{
    const float* node_feats = (const float*)d_in[0];
    const float* edge_feats = (const float*)d_in[1];
    const int*   src        = (const int*)d_in[2];
    const int*   dst        = (const int*)d_in[3];
    const float* We         = (const float*)d_in[4];
    const float* ln_e_g     = (const float*)d_in[5];
    const float* ln_e_b     = (const float*)d_in[6];
    const float* Wn         = (const float*)d_in[7];
    const float* ln_n_g     = (const float*)d_in[8];
    const float* ln_n_b     = (const float*)d_in[9];
    const float* Wo         = (const float*)d_in[10];
    const float* ln_o_g     = (const float*)d_in[11];
    const float* ln_o_b     = (const float*)d_in[12];
    const float* alphas     = (const float*)d_in[13];
    const float* beltas     = (const float*)d_in[14];
    float* out = (float*)d_out;

    float* x  = (float*)d_ws;                 // NN*D
    float* hv = x  + (size_t)NN * D;          // NN*D
    float* h  = hv + (size_t)NN * D;          // NN*D

    const int smb = (D * D + 32 * D) * sizeof(float);  // 81920 B
    hipFuncSetAttribute((const void*)proj_kernel<0>, hipFuncAttributeMaxDynamicSharedMemorySize, smb);
    hipFuncSetAttribute((const void*)proj_kernel<1>, hipFuncAttributeMaxDynamicSharedMemorySize, smb);
    hipFuncSetAttribute((const void*)edge_kernel,    hipFuncAttributeMaxDynamicSharedMemorySize, smb);

    const int NODE_CHUNKS = (NN + 31) / 32;   // 1563

    for (int i = 0; i < 3; ++i) {
        const float* gate = (i == 0) ? nullptr : (alphas + i);
        const float* xin = node_feats;
        if (i > 0) {
            prep_kernel<<<2048, 256, 0, stream>>>(out, node_feats, beltas + i, alphas + i, x);
            xin = x;
        }
        proj_kernel<0><<<NODE_CHUNKS, 256, smb, stream>>>(
            xin, Wn + (size_t)i * D * D, ln_n_g + i * D, ln_n_b + i * D, hv, NN, gate);
        hipMemsetAsync(h, 0, (size_t)NN * D * sizeof(float), stream);
        edge_kernel<<<2048, 256, smb, stream>>>(
            edge_feats, We + (size_t)i * D * D, ln_e_g + i * D, ln_e_b + i * D,
            hv, src, dst, h, gate);
        if (i == 0) {
            proj_kernel<0><<<NODE_CHUNKS, 256, smb, stream>>>(
                h, Wo, ln_o_g, ln_o_b, out, NN, nullptr);
        } else {
            proj_kernel<1><<<NODE_CHUNKS, 256, smb, stream>>>(
                h, Wo + (size_t)i * D * D, ln_o_g + i * D, ln_o_b + i * D, out, NN, alphas + i);
        }
    }
}